// Round 2
// baseline (295.075 us; speedup 1.0000x reference)
//
#include <hip/hip_runtime.h>
#include <hip/hip_bf16.h>

#define DIMD 768
#define RNK  48
#define KADP 4
#define NB   8
#define NS   4096
#define NKR  192          // KADP*RNK
#define GSTR 200          // g_lds row stride in bf16 elems (400B: 16B-aligned, <=2-way bank conflict)

typedef __attribute__((ext_vector_type(8))) short short8;
typedef __attribute__((ext_vector_type(4))) float floatx4;

__device__ __forceinline__ short f2bf(float f) {
    union { float f; unsigned u; } v; v.f = f;
    unsigned u = v.u;
    unsigned r = (u + 0x7fffu + ((u >> 16) & 1u)) >> 16;   // RNE
    return (short)(r & 0xffffu);
}

// ---------------------------------------------------------------------------
// Kernel 1: pack Wd/Wu into bf16 MFMA-B-fragment order; zero the pool buffer.
// Wd raw: [k, d, r]  ->  B-frag for down GEMM:  B[k=d][n=kr],   kr = k*48+r
// Wu raw: [k, r, d]  ->  B-frag for up GEMM:    B[k=kr][n=d]
// Packed addr (bf16): ((nt*KC + kc)*64 + lane)*8 + j
// ---------------------------------------------------------------------------
__global__ void prep_pack(const float* __restrict__ Wd, const float* __restrict__ Wu,
                          short* __restrict__ WdP, short* __restrict__ WuP,
                          float* __restrict__ pool) {
    int i = blockIdx.x * 256 + threadIdx.x;
    if (i < NB * DIMD) pool[i] = 0.0f;
    if (i < 18432) {                     // Wd: 12 nt * 24 kc * 64 lanes
        int lane = i & 63, tile = i >> 6;
        int kc = tile % 24, nt = tile / 24;
        int col = lane & 15, quad = lane >> 4;
        int kr = nt * 16 + col;
        int k = kr / RNK, r = kr % RNK;
        short8 vals;
#pragma unroll
        for (int j = 0; j < 8; ++j) {
            int d = kc * 32 + quad * 8 + j;
            vals[j] = f2bf(Wd[(k * DIMD + d) * RNK + r]);
        }
        *(short8*)(WdP + (size_t)i * 8) = vals;
    } else if (i < 36864) {              // Wu: 48 nt * 6 kc * 64 lanes
        int i2 = i - 18432;
        int lane = i2 & 63, tile = i2 >> 6;
        int kc = tile % 6, nt = tile / 6;
        int col = lane & 15, quad = lane >> 4;
        int d = nt * 16 + col;
        short8 vals;
#pragma unroll
        for (int j = 0; j < 8; ++j) {
            int krk = kc * 32 + quad * 8 + j;
            int k = krk / RNK, r = krk % RNK;
            vals[j] = f2bf(Wu[(k * RNK + r) * DIMD + d]);
        }
        *(short8*)(WuP + (size_t)i2 * 8) = vals;
    }
}

// ---------------------------------------------------------------------------
// Kernel 2: partial sums of x over S into pool[b,d] (atomic fp32).
// grid (1, 32, 8), block 192: thread covers 4 consecutive d, 128 s per block.
// 256 blocks -> 196k atomics (32-way contention), unroll 8 keeps ~24KB/CU in flight.
// ---------------------------------------------------------------------------
__global__ void pool_partial(const float* __restrict__ x, float* __restrict__ pool) {
    int b = blockIdx.z;
    int sc = blockIdx.y;              // 128 s-values per chunk
    int d4 = threadIdx.x * 4;
    const float* xp = x + ((size_t)(b * NS + sc * 128)) * DIMD + d4;
    float4 acc = {0.f, 0.f, 0.f, 0.f};
#pragma unroll 8
    for (int s = 0; s < 128; ++s) {
        float4 v = *(const float4*)(xp + (size_t)s * DIMD);
        acc.x += v.x; acc.y += v.y; acc.z += v.z; acc.w += v.w;
    }
    atomicAdd(&pool[b * DIMD + d4 + 0], acc.x);
    atomicAdd(&pool[b * DIMD + d4 + 1], acc.y);
    atomicAdd(&pool[b * DIMD + d4 + 2], acc.z);
    atomicAdd(&pool[b * DIMD + d4 + 3], acc.w);
}

// ---------------------------------------------------------------------------
// Kernel 3: router logits -> softmax w[b,k]; biasb[b,d] = sum_k w_k * bu[k,d].
// ---------------------------------------------------------------------------
__global__ void router_kernel(const float* __restrict__ pool, const float* __restrict__ Wr,
                              const float* __restrict__ br, const float* __restrict__ bu,
                              float* __restrict__ w_out, float* __restrict__ biasb) {
    __shared__ float y_lds[NB * KADP];
    __shared__ float w_lds[NB * KADP];
    int tid = threadIdx.x;
    int p = tid >> 3, l8 = tid & 7;      // 32 (b,k) pairs x 8 lanes
    int b = p >> 2, k = p & 3;
    float s = 0.f;
    for (int d = l8; d < DIMD; d += 8)
        s += pool[b * DIMD + d] * Wr[d * KADP + k];
#pragma unroll
    for (int m = 4; m >= 1; m >>= 1) s += __shfl_xor(s, m);
    if (l8 == 0) y_lds[p] = s * (1.0f / NS) + br[k];
    __syncthreads();
    if (tid < NB) {
        float y0 = y_lds[tid * 4 + 0], y1 = y_lds[tid * 4 + 1];
        float y2 = y_lds[tid * 4 + 2], y3 = y_lds[tid * 4 + 3];
        float mx = fmaxf(fmaxf(y0, y1), fmaxf(y2, y3));
        float e0 = __expf(y0 - mx), e1 = __expf(y1 - mx);
        float e2 = __expf(y2 - mx), e3 = __expf(y3 - mx);
        float inv = 1.0f / (e0 + e1 + e2 + e3);
        w_lds[tid * 4 + 0] = e0 * inv; w_lds[tid * 4 + 1] = e1 * inv;
        w_lds[tid * 4 + 2] = e2 * inv; w_lds[tid * 4 + 3] = e3 * inv;
        w_out[tid * 4 + 0] = e0 * inv; w_out[tid * 4 + 1] = e1 * inv;
        w_out[tid * 4 + 2] = e2 * inv; w_out[tid * 4 + 3] = e3 * inv;
    }
    __syncthreads();
    for (int b2 = 0; b2 < NB; ++b2) {
        float w0 = w_lds[b2 * 4 + 0], w1 = w_lds[b2 * 4 + 1];
        float w2 = w_lds[b2 * 4 + 2], w3 = w_lds[b2 * 4 + 3];
        for (int d = tid; d < DIMD; d += 256)
            biasb[b2 * DIMD + d] = w0 * bu[0 * DIMD + d] + w1 * bu[1 * DIMD + d]
                                 + w2 * bu[2 * DIMD + d] + w3 * bu[3 * DIMD + d];
    }
}

// ---------------------------------------------------------------------------
// Kernel 4: fused down-proj + GELU + router-scale + up-proj + bias.
// grid (32, 8), block 256 = 4 waves. Wave owns 32 tokens (TWO 16-row m-tiles):
// every B-fragment load now feeds 2 MFMAs -> L2 weight traffic halved vs 16-tok.
// MFMA 16x16x32 bf16 layouts (HW-verified):
//   A: lane holds A[m=lane&15][k=quad*8+j]      (j=0..7)
//   B: lane holds B[k=quad*8+j][n=lane&15]
//   C: lane holds C[row=quad*4+reg][col=lane&15] (reg=0..3)
// ---------------------------------------------------------------------------
__launch_bounds__(256, 1)
__global__ void adapter_main(const float* __restrict__ x,
                             const float* __restrict__ bd,
                             const short* __restrict__ WdP,
                             const short* __restrict__ WuP,
                             const float* __restrict__ w_vec,
                             const float* __restrict__ biasb,
                             float* __restrict__ out) {
    __shared__ short g_lds[128 * GSTR];     // 51.2 KB
    const int tid = threadIdx.x;
    const int wave = tid >> 6, lane = tid & 63;
    const int col = lane & 15, quad = lane >> 4;
    const int b = blockIdx.y;
    const int s0 = blockIdx.x * 128 + wave * 32;   // this wave's 32-token base

    // ---- Phase 1: h[32 tokens x 192 kr] = x_tile[32x768] * WdB[768x192] ----
    floatx4 acc[2][12];
#pragma unroll
    for (int mt = 0; mt < 2; ++mt)
#pragma unroll
        for (int nt = 0; nt < 12; ++nt) acc[mt][nt] = (floatx4){0.f, 0.f, 0.f, 0.f};

    const float* xl0 = x + ((size_t)(b * NS + s0 + col)) * DIMD + quad * 8;
    const float* xl1 = xl0 + 16 * DIMD;
    for (int kc = 0; kc < 24; ++kc) {
        float4 a00 = *(const float4*)(xl0 + kc * 32);
        float4 a01 = *(const float4*)(xl0 + kc * 32 + 4);
        float4 a10 = *(const float4*)(xl1 + kc * 32);
        float4 a11 = *(const float4*)(xl1 + kc * 32 + 4);
        short8 af0, af1;
        af0[0] = f2bf(a00.x); af0[1] = f2bf(a00.y); af0[2] = f2bf(a00.z); af0[3] = f2bf(a00.w);
        af0[4] = f2bf(a01.x); af0[5] = f2bf(a01.y); af0[6] = f2bf(a01.z); af0[7] = f2bf(a01.w);
        af1[0] = f2bf(a10.x); af1[1] = f2bf(a10.y); af1[2] = f2bf(a10.z); af1[3] = f2bf(a10.w);
        af1[4] = f2bf(a11.x); af1[5] = f2bf(a11.y); af1[6] = f2bf(a11.z); af1[7] = f2bf(a11.w);
#pragma unroll
        for (int nt = 0; nt < 12; ++nt) {
            short8 bf = *(const short8*)(WdP + ((size_t)(nt * 24 + kc) * 64 + lane) * 8);
            acc[0][nt] = __builtin_amdgcn_mfma_f32_16x16x32_bf16(af0, bf, acc[0][nt], 0, 0, 0);
            acc[1][nt] = __builtin_amdgcn_mfma_f32_16x16x32_bf16(af1, bf, acc[1][nt], 0, 0, 0);
        }
    }

    // ---- epilogue: +bd, tanh-GELU, *w_k, bf16 -> LDS (C-layout -> A-layout) ----
    float4 wv = *(const float4*)(w_vec + b * 4);
#pragma unroll
    for (int mt = 0; mt < 2; ++mt) {
#pragma unroll
        for (int nt = 0; nt < 12; ++nt) {
            int kr = nt * 16 + col;
            float bdv = bd[kr];
            int k = kr / RNK;
            float wk = (k == 0) ? wv.x : (k == 1) ? wv.y : (k == 2) ? wv.z : wv.w;
#pragma unroll
            for (int reg = 0; reg < 4; ++reg) {
                float h = acc[mt][nt][reg] + bdv;
                float zz = 0.7978845608028654f * (h + 0.044715f * h * h * h);
                float e = __expf(2.0f * zz);
                float th = 1.0f - 2.0f / (e + 1.0f);      // tanh(zz)
                float g = 0.5f * h * (1.0f + th) * wk;
                int row = wave * 32 + mt * 16 + quad * 4 + reg;
                g_lds[row * GSTR + kr] = f2bf(g);
            }
        }
    }
    __syncthreads();

    // ---- Phase 2: out[32 x 768] = g[32 x 192] * WuB[192 x 768] ----
    short8 ga[2][6];
#pragma unroll
    for (int mt = 0; mt < 2; ++mt)
#pragma unroll
        for (int kc = 0; kc < 6; ++kc)
            ga[mt][kc] = *(const short8*)(g_lds + (wave * 32 + mt * 16 + col) * GSTR + kc * 32 + quad * 8);

    float* outw = out + ((size_t)(b * NS + s0)) * DIMD;
    for (int nt = 0; nt < 48; nt += 2) {
        floatx4 c00 = (floatx4){0.f, 0.f, 0.f, 0.f};
        floatx4 c01 = (floatx4){0.f, 0.f, 0.f, 0.f};
        floatx4 c10 = (floatx4){0.f, 0.f, 0.f, 0.f};
        floatx4 c11 = (floatx4){0.f, 0.f, 0.f, 0.f};
#pragma unroll
        for (int kc = 0; kc < 6; ++kc) {
            short8 b0 = *(const short8*)(WuP + ((size_t)((nt + 0) * 6 + kc) * 64 + lane) * 8);
            short8 b1 = *(const short8*)(WuP + ((size_t)((nt + 1) * 6 + kc) * 64 + lane) * 8);
            c00 = __builtin_amdgcn_mfma_f32_16x16x32_bf16(ga[0][kc], b0, c00, 0, 0, 0);
            c01 = __builtin_amdgcn_mfma_f32_16x16x32_bf16(ga[0][kc], b1, c01, 0, 0, 0);
            c10 = __builtin_amdgcn_mfma_f32_16x16x32_bf16(ga[1][kc], b0, c10, 0, 0, 0);
            c11 = __builtin_amdgcn_mfma_f32_16x16x32_bf16(ga[1][kc], b1, c11, 0, 0, 0);
        }
        int d0 = (nt + 0) * 16 + col, d1 = (nt + 1) * 16 + col;
        float bb0 = biasb[b * DIMD + d0];
        float bb1 = biasb[b * DIMD + d1];
#pragma unroll
        for (int reg = 0; reg < 4; ++reg) {
            int r0 = quad * 4 + reg;
            outw[(size_t)(r0) * DIMD + d0]      = c00[reg] + bb0;
            outw[(size_t)(r0) * DIMD + d1]      = c01[reg] + bb1;
            outw[(size_t)(r0 + 16) * DIMD + d0] = c10[reg] + bb0;
            outw[(size_t)(r0 + 16) * DIMD + d1] = c11[reg] + bb1;
        }
    }
}

// ---------------------------------------------------------------------------
extern "C" void kernel_launch(void* const* d_in, const int* in_sizes, int n_in,
                              void* d_out, int out_size, void* d_ws, size_t ws_size,
                              hipStream_t stream) {
    const float* x  = (const float*)d_in[0];
    const float* Wd = (const float*)d_in[1];
    const float* bd = (const float*)d_in[2];
    const float* Wu = (const float*)d_in[3];
    const float* bu = (const float*)d_in[4];
    const float* Wr = (const float*)d_in[5];
    const float* br = (const float*)d_in[6];
    float* out = (float*)d_out;

    char* ws = (char*)d_ws;
    float* pool  = (float*)(ws);               // 6144 f32 = 24576 B
    float* w_vec = (float*)(ws + 24576);       // 32 f32   = 128 B
    float* biasb = (float*)(ws + 24704);       // 6144 f32 = 24576 B
    short* WdP   = (short*)(ws + 49280);       // 147456 bf16 = 294912 B
    short* WuP   = (short*)(ws + 344192);      // 147456 bf16 = 294912 B
    // total ws usage: 639104 B

    prep_pack<<<144, 256, 0, stream>>>(Wd, Wu, WdP, WuP, pool);
    pool_partial<<<dim3(1, 32, 8), 192, 0, stream>>>(x, pool);
    router_kernel<<<1, 256, 0, stream>>>(pool, Wr, br, bu, w_vec, biasb);
    adapter_main<<<dim3(32, 8), 256, 0, stream>>>(x, bd, WdP, WuP, w_vec, biasb, out);
}

// Round 3
// 279.225 us; speedup vs baseline: 1.0568x; 1.0568x over previous
//
#include <hip/hip_runtime.h>
#include <hip/hip_bf16.h>

#define DIMD 768
#define RNK  48
#define KADP 4
#define NB   8
#define NS   4096
#define NKR  192
#define GSTR 200          // g region row stride (bf16 elems)
#define XSTR 776          // x_lds row stride (bf16 elems); 1552B rows, 16B aligned

typedef __attribute__((ext_vector_type(8))) short short8;
typedef __attribute__((ext_vector_type(4))) short short4v;
typedef __attribute__((ext_vector_type(4))) float floatx4;

__device__ __forceinline__ short f2bf(float f) {
    union { float f; unsigned u; } v; v.f = f;
    unsigned u = v.u;
    unsigned r = (u + 0x7fffu + ((u >> 16) & 1u)) >> 16;   // RNE
    return (short)(r & 0xffffu);
}

// ---------------------------------------------------------------------------
// Prologue: blocks 0..255 = pool partial sums; blocks 256..399 = weight pack.
// pool must be zeroed by hipMemsetAsync before this kernel.
// Wd raw [k,d,r] -> down-B-frag: B[k=d][n=kr], kr=k*48+r
// Wu raw [k,r,d] -> up-B-frag:   B[k=kr][n=d]
// Packed addr (bf16): ((nt*KC + kc)*64 + lane)*8 + j ; k-in-chunk = quad*8+j
// ---------------------------------------------------------------------------
__global__ void prologue(const float* __restrict__ x,
                         const float* __restrict__ Wd, const float* __restrict__ Wu,
                         short* __restrict__ WdP, short* __restrict__ WuP,
                         float* __restrict__ pool) {
    int blk = blockIdx.x;
    int tid = threadIdx.x;
    if (blk < 256) {                      // ---- pool partial ----
        if (tid >= 192) return;
        int b = blk >> 5, sc = blk & 31;  // 128 s per block
        int d4 = tid * 4;
        const float* xp = x + ((size_t)(b * NS + sc * 128)) * DIMD + d4;
        float4 acc = {0.f, 0.f, 0.f, 0.f};
#pragma unroll 8
        for (int s = 0; s < 128; ++s) {
            float4 v = *(const float4*)(xp + (size_t)s * DIMD);
            acc.x += v.x; acc.y += v.y; acc.z += v.z; acc.w += v.w;
        }
        atomicAdd(&pool[b * DIMD + d4 + 0], acc.x);
        atomicAdd(&pool[b * DIMD + d4 + 1], acc.y);
        atomicAdd(&pool[b * DIMD + d4 + 2], acc.z);
        atomicAdd(&pool[b * DIMD + d4 + 3], acc.w);
        return;
    }
    int i = (blk - 256) * 256 + tid;      // ---- weight pack ----
    if (i < 18432) {                      // Wd: 12 nt * 24 kc * 64 lanes
        int lane = i & 63, tile = i >> 6;
        int kc = tile % 24, nt = tile / 24;
        int col = lane & 15, quad = lane >> 4;
        int kr = nt * 16 + col;
        int k = kr / RNK, r = kr % RNK;
        short8 vals;
#pragma unroll
        for (int j = 0; j < 8; ++j) {
            int d = kc * 32 + quad * 8 + j;
            vals[j] = f2bf(Wd[(k * DIMD + d) * RNK + r]);
        }
        *(short8*)(WdP + (size_t)i * 8) = vals;
    } else if (i < 36864) {               // Wu: 48 nt * 6 kc * 64 lanes
        int i2 = i - 18432;
        int lane = i2 & 63, tile = i2 >> 6;
        int kc = tile % 6, nt = tile / 6;
        int col = lane & 15, quad = lane >> 4;
        int d = nt * 16 + col;
        short8 vals;
#pragma unroll
        for (int j = 0; j < 8; ++j) {
            int krk = kc * 32 + quad * 8 + j;
            int k = krk / RNK, r = krk % RNK;
            vals[j] = f2bf(Wu[(k * RNK + r) * DIMD + d]);
        }
        *(short8*)(WuP + (size_t)i2 * 8) = vals;
    }
}

// ---------------------------------------------------------------------------
// Router: softmax over pooled logits; biasb[b,d] = sum_k w_k * bu[k,d].
// ---------------------------------------------------------------------------
__global__ void router_kernel(const float* __restrict__ pool, const float* __restrict__ Wr,
                              const float* __restrict__ br, const float* __restrict__ bu,
                              float* __restrict__ w_out, float* __restrict__ biasb) {
    __shared__ float y_lds[NB * KADP];
    __shared__ float w_lds[NB * KADP];
    int tid = threadIdx.x;
    int p = tid >> 3, l8 = tid & 7;
    int b = p >> 2, k = p & 3;
    float s = 0.f;
    for (int d = l8; d < DIMD; d += 8)
        s += pool[b * DIMD + d] * Wr[d * KADP + k];
#pragma unroll
    for (int m = 4; m >= 1; m >>= 1) s += __shfl_xor(s, m);
    if (l8 == 0) y_lds[p] = s * (1.0f / NS) + br[k];
    __syncthreads();
    if (tid < NB) {
        float y0 = y_lds[tid * 4 + 0], y1 = y_lds[tid * 4 + 1];
        float y2 = y_lds[tid * 4 + 2], y3 = y_lds[tid * 4 + 3];
        float mx = fmaxf(fmaxf(y0, y1), fmaxf(y2, y3));
        float e0 = __expf(y0 - mx), e1 = __expf(y1 - mx);
        float e2 = __expf(y2 - mx), e3 = __expf(y3 - mx);
        float inv = 1.0f / (e0 + e1 + e2 + e3);
        w_lds[tid * 4 + 0] = e0 * inv; w_lds[tid * 4 + 1] = e1 * inv;
        w_lds[tid * 4 + 2] = e2 * inv; w_lds[tid * 4 + 3] = e3 * inv;
        w_out[tid * 4 + 0] = e0 * inv; w_out[tid * 4 + 1] = e1 * inv;
        w_out[tid * 4 + 2] = e2 * inv; w_out[tid * 4 + 3] = e3 * inv;
    }
    __syncthreads();
    for (int b2 = 0; b2 < NB; ++b2) {
        float w0 = w_lds[b2 * 4 + 0], w1 = w_lds[b2 * 4 + 1];
        float w2 = w_lds[b2 * 4 + 2], w3 = w_lds[b2 * 4 + 3];
        for (int d = tid; d < DIMD; d += 256)
            biasb[b2 * DIMD + d] = w0 * bu[0 * DIMD + d] + w1 * bu[1 * DIMD + d]
                                 + w2 * bu[2 * DIMD + d] + w3 * bu[3 * DIMD + d];
    }
}

// ---------------------------------------------------------------------------
// Main: grid(128,8), block 256 = 4 waves. Block owns 32 tokens (2 m-tiles),
// staged once in LDS as bf16. Wave w owns BOTH m-tiles x one n-quarter:
//   phase 1: nt = 3w..3w+2 (48 kr);  phase 2: nt = 12w..12w+11 (192 d).
// m-reuse=2 per B-frag (halved L2 weight traffic) AND 1024 blocks (3/CU by
// LDS=49.7KB -> 12 waves/CU, 2x round-1 occupancy).
// MFMA 16x16x32 bf16 layouts (HW-verified):
//   A: lane holds A[m=lane&15][k=quad*8+j] ; B: B[k=quad*8+j][n=lane&15]
//   C: lane holds C[row=quad*4+reg][col=lane&15]
// ---------------------------------------------------------------------------
__launch_bounds__(256, 3)
__global__ void adapter_main(const float* __restrict__ x,
                             const float* __restrict__ bd,
                             const short* __restrict__ WdP,
                             const short* __restrict__ WuP,
                             const float* __restrict__ w_vec,
                             const float* __restrict__ biasb,
                             float* __restrict__ out) {
    __shared__ short smem[32 * XSTR];          // 49664 B; g region aliases front
    const int tid = threadIdx.x;
    const int wave = tid >> 6, lane = tid & 63;
    const int col = lane & 15, quad = lane >> 4;
    const int b = blockIdx.y;
    const int s0 = blockIdx.x * 32;

    // ---- stage x tile [32 x 768] -> LDS bf16 (row-major, stride XSTR) ----
    const float* xb = x + ((size_t)(b * NS + s0)) * DIMD;
    for (int i = tid; i < 6144; i += 256) {    // 6144 float4 = 32*768 elems
        int row = i / 192, kf = i % 192;
        float4 v = *(const float4*)(xb + (size_t)row * DIMD + kf * 4);
        short4v sv;
        sv[0] = f2bf(v.x); sv[1] = f2bf(v.y); sv[2] = f2bf(v.z); sv[3] = f2bf(v.w);
        *(short4v*)(smem + row * XSTR + kf * 4) = sv;
    }
    __syncthreads();

    // ---- Phase 1: h[32 x 48] (this wave's kr quarter) ----
    floatx4 acc[2][3];
#pragma unroll
    for (int mt = 0; mt < 2; ++mt)
#pragma unroll
        for (int j = 0; j < 3; ++j) acc[mt][j] = (floatx4){0.f, 0.f, 0.f, 0.f};

    const short* xl0 = smem + col * XSTR;
    const short* xl1 = smem + (16 + col) * XSTR;
    const int ntb = wave * 3;
    for (int kc = 0; kc < 24; ++kc) {
        short8 a0 = *(const short8*)(xl0 + kc * 32 + quad * 8);
        short8 a1 = *(const short8*)(xl1 + kc * 32 + quad * 8);
#pragma unroll
        for (int j = 0; j < 3; ++j) {
            short8 bf = *(const short8*)(WdP + ((size_t)((ntb + j) * 24 + kc) * 64 + lane) * 8);
            acc[0][j] = __builtin_amdgcn_mfma_f32_16x16x32_bf16(a0, bf, acc[0][j], 0, 0, 0);
            acc[1][j] = __builtin_amdgcn_mfma_f32_16x16x32_bf16(a1, bf, acc[1][j], 0, 0, 0);
        }
    }
    __syncthreads();    // all x_lds reads done before g overwrites the region

    // ---- epilogue: +bd, tanh-GELU, *w_k, bf16 -> g region (C -> A layout) ----
    float4 wv = *(const float4*)(w_vec + b * 4);
#pragma unroll
    for (int mt = 0; mt < 2; ++mt) {
#pragma unroll
        for (int j = 0; j < 3; ++j) {
            int kr = (ntb + j) * 16 + col;
            float bdv = bd[kr];
            int k = kr / RNK;
            float wk = (k == 0) ? wv.x : (k == 1) ? wv.y : (k == 2) ? wv.z : wv.w;
#pragma unroll
            for (int reg = 0; reg < 4; ++reg) {
                float h = acc[mt][j][reg] + bdv;
                float zz = 0.7978845608028654f * (h + 0.044715f * h * h * h);
                float e = __expf(2.0f * zz);
                float th = 1.0f - 2.0f / (e + 1.0f);      // tanh(zz)
                float g = 0.5f * h * (1.0f + th) * wk;
                int row = mt * 16 + quad * 4 + reg;
                smem[row * GSTR + kr] = f2bf(g);
            }
        }
    }
    __syncthreads();

    // ---- Phase 2: out[32 x 192] (this wave's d quarter) ----
    short8 ga[2][6];
#pragma unroll
    for (int mt = 0; mt < 2; ++mt)
#pragma unroll
        for (int kc = 0; kc < 6; ++kc)
            ga[mt][kc] = *(const short8*)(smem + (mt * 16 + col) * GSTR + kc * 32 + quad * 8);

    float* outw = out + ((size_t)(b * NS + s0)) * DIMD;
    const int ntb2 = wave * 12;
    for (int p = 0; p < 6; ++p) {
        int nt = ntb2 + p * 2;
        floatx4 c00 = (floatx4){0.f, 0.f, 0.f, 0.f};
        floatx4 c01 = (floatx4){0.f, 0.f, 0.f, 0.f};
        floatx4 c10 = (floatx4){0.f, 0.f, 0.f, 0.f};
        floatx4 c11 = (floatx4){0.f, 0.f, 0.f, 0.f};
#pragma unroll
        for (int kc = 0; kc < 6; ++kc) {
            short8 b0 = *(const short8*)(WuP + ((size_t)((nt + 0) * 6 + kc) * 64 + lane) * 8);
            short8 b1 = *(const short8*)(WuP + ((size_t)((nt + 1) * 6 + kc) * 64 + lane) * 8);
            c00 = __builtin_amdgcn_mfma_f32_16x16x32_bf16(ga[0][kc], b0, c00, 0, 0, 0);
            c01 = __builtin_amdgcn_mfma_f32_16x16x32_bf16(ga[0][kc], b1, c01, 0, 0, 0);
            c10 = __builtin_amdgcn_mfma_f32_16x16x32_bf16(ga[1][kc], b0, c10, 0, 0, 0);
            c11 = __builtin_amdgcn_mfma_f32_16x16x32_bf16(ga[1][kc], b1, c11, 0, 0, 0);
        }
        int d0 = (nt + 0) * 16 + col, d1 = (nt + 1) * 16 + col;
        float bb0 = biasb[b * DIMD + d0];
        float bb1 = biasb[b * DIMD + d1];
#pragma unroll
        for (int reg = 0; reg < 4; ++reg) {
            int r0 = quad * 4 + reg;
            outw[(size_t)(r0) * DIMD + d0]      = c00[reg] + bb0;
            outw[(size_t)(r0) * DIMD + d1]      = c01[reg] + bb1;
            outw[(size_t)(r0 + 16) * DIMD + d0] = c10[reg] + bb0;
            outw[(size_t)(r0 + 16) * DIMD + d1] = c11[reg] + bb1;
        }
    }
}

// ---------------------------------------------------------------------------
extern "C" void kernel_launch(void* const* d_in, const int* in_sizes, int n_in,
                              void* d_out, int out_size, void* d_ws, size_t ws_size,
                              hipStream_t stream) {
    const float* x  = (const float*)d_in[0];
    const float* Wd = (const float*)d_in[1];
    const float* bd = (const float*)d_in[2];
    const float* Wu = (const float*)d_in[3];
    const float* bu = (const float*)d_in[4];
    const float* Wr = (const float*)d_in[5];
    const float* br = (const float*)d_in[6];
    float* out = (float*)d_out;

    char* ws = (char*)d_ws;
    float* pool  = (float*)(ws);               // 6144 f32 = 24576 B
    float* w_vec = (float*)(ws + 24576);       // 32 f32   = 128 B
    float* biasb = (float*)(ws + 24704);       // 6144 f32 = 24576 B
    short* WdP   = (short*)(ws + 49280);       // 147456 bf16 = 294912 B
    short* WuP   = (short*)(ws + 344192);      // 147456 bf16 = 294912 B

    hipMemsetAsync(pool, 0, NB * DIMD * sizeof(float), stream);
    prologue<<<400, 256, 0, stream>>>(x, Wd, Wu, WdP, WuP, pool);
    router_kernel<<<1, 256, 0, stream>>>(pool, Wr, br, bu, w_vec, biasb);
    adapter_main<<<dim3(128, 8), 256, 0, stream>>>(x, bd, WdP, WuP, w_vec, biasb, out);
}